// Round 2
// baseline (380.056 us; speedup 1.0000x reference)
//
#include <hip/hip_runtime.h>
#include <hip/hip_bf16.h>

typedef __attribute__((ext_vector_type(8))) short bf16x8;
typedef __attribute__((ext_vector_type(4))) float f32x4;
typedef unsigned short u16;

#define BM 128
#define BN 128
#define BK 64
#define BATCH 100000
#define EPE 200000

// ---- workspace layout (bytes) ----
#define OFF_AP    ((size_t)0)          // u16 [1024*1024]  A padded
#define OFF_ATP   ((size_t)2097152)    // u16 [1024*1024]  A^T padded
#define OFF_SP    ((size_t)4194304)    // u16 [1024*1024]  S = A A^T
#define OFF_G     ((size_t)6291456)    // f32 [1024*1024]  masked/divided gamma (upper block)
#define OFF_GNS   ((size_t)10485760)   // u16 [1024*1024]  row-normalized gamma (src rows)
#define OFF_GNDT  ((size_t)12582912)   // u16 [1024*1024]  col-normalized gamma^T (dst rows)
#define OFF_W1AT  ((size_t)14680064)   // u16 [256*1024]
#define OFF_W1BT  ((size_t)15204352)   // u16 [256*1024]
#define OFF_W2T   ((size_t)15728640)   // u16 [128*256]
#define OFF_HID   ((size_t)15794176)   // u16 [2048*256]
#define OFF_DEGS  ((size_t)16842752)   // f32 [1024]
#define OFF_DEGD  ((size_t)16846848)   // f32 [1024]
#define OFF_CN    ((size_t)16850944)   // f32 [1024]
#define OFF_PART  ((size_t)16855040)   // f32 [6250]
#define OFF_H     ((size_t)16896000)   // f32 [2000*256]

__device__ __forceinline__ u16 f2b(float f) {
  union { float f; unsigned u; } v; v.f = f;
  unsigned r = v.u + 0x7fffu + ((v.u >> 16) & 1u);
  return (u16)(r >> 16);
}
__device__ __forceinline__ float b2f(u16 h) {
  union { unsigned u; float f; } v; v.u = ((unsigned)h) << 16;
  return v.f;
}

#define AS1C(p) ((const __attribute__((address_space(1))) void*)(p))
#define AS3(p)  ((__attribute__((address_space(3))) void*)(p))

// ---------------- pack kernels ----------------
// A block = adj[0:1000, 1000:2000], padded to 1024x1024 bf16
__global__ __launch_bounds__(256) void pack_A(const float* __restrict__ adj, u16* __restrict__ Ap) {
  int idx = blockIdx.x * 256 + threadIdx.x;       // 1024*1024
  int r = idx >> 10, c = idx & 1023;
  float v = (r < 1000 && c < 1000) ? adj[(size_t)r * 2000 + 1000 + c] : 0.f;
  Ap[idx] = f2b(v);
}

// A^T padded, via 64x64 LDS tiles (coalesced both sides)
__global__ __launch_bounds__(256) void transpose_packA(const float* __restrict__ adj, u16* __restrict__ ATp) {
  __shared__ float tile[64][65];
  int tr = blockIdx.x, tc = blockIdx.y;
  int tx = threadIdx.x & 63, ty = threadIdx.x >> 6;
  #pragma unroll
  for (int p = 0; p < 16; p++) {
    int r = ty + p * 4;
    int gr = tr * 64 + r, gc = tc * 64 + tx;
    tile[r][tx] = (gr < 1000 && gc < 1000) ? adj[(size_t)gr * 2000 + 1000 + gc] : 0.f;
  }
  __syncthreads();
  #pragma unroll
  for (int p = 0; p < 16; p++) {
    int r = ty + p * 4;
    ATp[(size_t)(tc * 64 + r) * 1024 + tr * 64 + tx] = f2b(tile[tx][r]);
  }
}

// W1 split halves, transposed: W1At[h][i] = W1[i][h] (i<1000), W1Bt[h][j] = W1[1000+j][h]
__global__ __launch_bounds__(256) void pack_w1t(const float* __restrict__ W1,
                                                u16* __restrict__ W1At, u16* __restrict__ W1Bt) {
  int idx = blockIdx.x * 256 + threadIdx.x;       // 256*1024
  int h = idx >> 10, j = idx & 1023;
  float a = (j < 1000) ? W1[(size_t)j * 256 + h] : 0.f;
  float b = (j < 1000) ? W1[(size_t)(1000 + j) * 256 + h] : 0.f;
  W1At[idx] = f2b(a);
  W1Bt[idx] = f2b(b);
}

__global__ __launch_bounds__(256) void pack_w2t(const float* __restrict__ W2, u16* __restrict__ w2t) {
  int idx = blockIdx.x * 256 + threadIdx.x;       // 128*256
  int d = idx >> 8, k = idx & 255;
  w2t[idx] = f2b(W2[(size_t)k * 128 + d]);
}

__global__ __launch_bounds__(256) void copy_nodeh(const float* __restrict__ ne, float* __restrict__ h) {
  int idx = blockIdx.x * 256 + threadIdx.x;       // 2000*128
  int i = idx >> 7, d = idx & 127;
  h[(size_t)i * 256 + d] = ne[idx];
}

// column sums of a u16 bf16 [1024][1024] matrix -> f32[1024]
__global__ __launch_bounds__(256) void colsum16(const u16* __restrict__ M, float* __restrict__ outv) {
  __shared__ float red[8][32];
  int cx = threadIdx.x & 31, ry = threadIdx.x >> 5;
  int j = blockIdx.x * 32 + cx;
  float s = 0.f;
  for (int r = ry; r < 1024; r += 8) s += b2f(M[(size_t)r * 1024 + j]);
  red[ry][cx] = s;
  __syncthreads();
  if (ry == 0) {
    float t = 0.f;
    #pragma unroll
    for (int k = 0; k < 8; k++) t += red[k][cx];
    outv[j] = t;
  }
}

// column norms of f32 G -> cn[j] = sqrt(sum_r G[r][j]^2)
__global__ __launch_bounds__(256) void cnorm(const float* __restrict__ G, float* __restrict__ cn) {
  __shared__ float red[8][32];
  int cx = threadIdx.x & 31, ry = threadIdx.x >> 5;
  int j = blockIdx.x * 32 + cx;
  float s = 0.f;
  for (int r = ry; r < 1024; r += 8) { float g = G[(size_t)r * 1024 + j]; s += g * g; }
  red[ry][cx] = s;
  __syncthreads();
  if (ry == 0) {
    float t = 0.f;
    #pragma unroll
    for (int k = 0; k < 8; k++) t += red[k][cx];
    cn[j] = sqrtf(t);
  }
}

// per-row: norm + scale + bf16 store (src rows of gamma)
__global__ __launch_bounds__(256) void rnorm_scale(const float* __restrict__ G, u16* __restrict__ Gns) {
  __shared__ float red[256];
  int i = blockIdx.x;
  const float* row = G + (size_t)i * 1024;
  float v[4];
  float s = 0.f;
  #pragma unroll
  for (int c = 0; c < 4; c++) { v[c] = row[threadIdx.x + 256 * c]; s += v[c] * v[c]; }
  red[threadIdx.x] = s;
  __syncthreads();
  for (int off = 128; off > 0; off >>= 1) {
    if (threadIdx.x < off) red[threadIdx.x] += red[threadIdx.x + off];
    __syncthreads();
  }
  float inv = 1.0f / fmaxf(sqrtf(red[0]), 1e-12f);
  u16* orow = Gns + (size_t)i * 1024;
  #pragma unroll
  for (int c = 0; c < 4; c++) orow[threadIdx.x + 256 * c] = f2b(v[c] * inv);
}

// Gn_dstT[c][r] = G[r][c] / max(cn[c],1e-12), 64x64 LDS tile transpose
__global__ __launch_bounds__(256) void transpose_scale(const float* __restrict__ G,
                                                       const float* __restrict__ cn,
                                                       u16* __restrict__ Gndt) {
  __shared__ float tile[64][65];
  int tr = blockIdx.x, tc = blockIdx.y;
  int tx = threadIdx.x & 63, ty = threadIdx.x >> 6;
  #pragma unroll
  for (int p = 0; p < 16; p++) {
    int r = ty + p * 4;
    tile[r][tx] = G[(size_t)(tr * 64 + r) * 1024 + tc * 64 + tx];
  }
  __syncthreads();
  #pragma unroll
  for (int p = 0; p < 16; p++) {
    int r = ty + p * 4;
    int oc = tc * 64 + r;
    float inv = 1.0f / fmaxf(cn[oc], 1e-12f);
    Gndt[(size_t)oc * 1024 + tr * 64 + tx] = f2b(tile[tx][r] * inv);
  }
}

// ---------------- bf16 MFMA GEMM (C = A * BT^T) ----------------
// EPI 0: store bf16 C
// EPI 1: G = C * A / (degs[r]*degd[c]), store f32
// EPI 2: store bf16 tanh(C + bias[col]) at outb[row*256+col]
// EPI 3: h[:,128:] = C + bias  (row->node mapping for 2048-row stacked hid)
template <int EPI>
__global__ __launch_bounds__(256) void gemm_bt(
    const u16* __restrict__ A, const u16* __restrict__ BT,
    int K, int lda, int ldbt,
    u16* __restrict__ outb, int ldo,
    float* __restrict__ outf,
    const u16* __restrict__ apack,
    const float* __restrict__ degs,
    const float* __restrict__ degd,
    const float* __restrict__ bias,
    float* __restrict__ hout)
{
  __shared__ u16 As[BM * BK];
  __shared__ u16 Bs[BN * BK];
  const int t = threadIdx.x;
  const int w = t >> 6, lane = t & 63;
  const int brow = blockIdx.x * BM, bcol = blockIdx.y * BN;
  const int wr = w >> 1, wc = w & 1;
  const int r16 = lane & 15, kg = lane >> 4;

  f32x4 acc[4][4];
  #pragma unroll
  for (int m = 0; m < 4; m++)
    #pragma unroll
    for (int n = 0; n < 4; n++) {
      f32x4 z = {0.f, 0.f, 0.f, 0.f};
      acc[m][n] = z;
    }

  for (int k0 = 0; k0 < K; k0 += BK) {
    #pragma unroll
    for (int it = 0; it < 4; ++it) {
      int chunk = it * 256 + t;
      int row = chunk >> 3, cc = chunk & 7;
      const u16* ga = A + (size_t)(brow + row) * lda + k0 + cc * 8;
      __builtin_amdgcn_global_load_lds(AS1C(ga), AS3(As + (size_t)(it * 256 + w * 64) * 8), 16, 0, 0);
      const u16* gb = BT + (size_t)(bcol + row) * ldbt + k0 + cc * 8;
      __builtin_amdgcn_global_load_lds(AS1C(gb), AS3(Bs + (size_t)(it * 256 + w * 64) * 8), 16, 0, 0);
    }
    __syncthreads();
    #pragma unroll
    for (int kk = 0; kk < 2; ++kk) {
      bf16x8 af[4], bfr[4];
      #pragma unroll
      for (int m = 0; m < 4; m++)
        af[m] = *(const bf16x8*)&As[(wr * 64 + m * 16 + r16) * BK + kk * 32 + kg * 8];
      #pragma unroll
      for (int n = 0; n < 4; n++)
        bfr[n] = *(const bf16x8*)&Bs[(wc * 64 + n * 16 + r16) * BK + kk * 32 + kg * 8];
      #pragma unroll
      for (int m = 0; m < 4; m++)
        #pragma unroll
        for (int n = 0; n < 4; n++)
          acc[m][n] = __builtin_amdgcn_mfma_f32_16x16x32_bf16(af[m], bfr[n], acc[m][n], 0, 0, 0);
    }
    __syncthreads();
  }

  #pragma unroll
  for (int m = 0; m < 4; m++) {
    #pragma unroll
    for (int n = 0; n < 4; n++) {
      #pragma unroll
      for (int j = 0; j < 4; j++) {
        int row = brow + wr * 64 + m * 16 + kg * 4 + j;
        int col = bcol + wc * 64 + n * 16 + r16;
        float val = acc[m][n][j];
        if constexpr (EPI == 0) {
          outb[(size_t)row * ldo + col] = f2b(val);
        } else if constexpr (EPI == 1) {
          float a = b2f(apack[(size_t)row * 1024 + col]);
          float p2 = degs[row] * degd[col];
          float g = (p2 > 0.f) ? (val * a) / p2 : 0.f;
          outf[(size_t)row * 1024 + col] = g;
        } else if constexpr (EPI == 2) {
          outb[(size_t)row * 256 + col] = f2b(tanhf(val + bias[col]));
        } else {
          int node; bool valid;
          if (row < 1024) { node = row; valid = (row < 1000); }
          else            { node = row - 24; valid = (row < 2024); }
          if (valid) hout[(size_t)node * 256 + 128 + col] = val + bias[col];
        }
      }
    }
  }
}

// ---------------- skipgram loss: 16 lanes per sample ----------------
__global__ __launch_bounds__(256) void skipgram(const float* __restrict__ ne, const float* __restrict__ ce,
    const int* __restrict__ pu, const int* __restrict__ pv, const int* __restrict__ nv,
    float* __restrict__ partial) {
  __shared__ float red[16];
  int g = threadIdx.x >> 4;
  int l = threadIdx.x & 15;
  int s = blockIdx.x * 16 + g;          // 6250*16 = 100000 exactly

  const float4* u = (const float4*)(ne + (size_t)pu[s] * 128);
  const float4* v = (const float4*)(ce + (size_t)pv[s] * 128);
  const int* nvb = nv + (size_t)s * 5;
  const float4* n0 = (const float4*)(ce + (size_t)nvb[0] * 128);
  const float4* n1 = (const float4*)(ce + (size_t)nvb[1] * 128);
  const float4* n2 = (const float4*)(ce + (size_t)nvb[2] * 128);
  const float4* n3 = (const float4*)(ce + (size_t)nvb[3] * 128);
  const float4* n4 = (const float4*)(ce + (size_t)nvb[4] * 128);

  float4 ua = u[l], ub = u[l + 16];
  float ap, a0, a1, a2, a3, a4;
  {
    float4 xa, xb;
    xa = v[l];  xb = v[l + 16];
    ap = ua.x * xa.x + ua.y * xa.y + ua.z * xa.z + ua.w * xa.w
       + ub.x * xb.x + ub.y * xb.y + ub.z * xb.z + ub.w * xb.w;
    xa = n0[l]; xb = n0[l + 16];
    a0 = ua.x * xa.x + ua.y * xa.y + ua.z * xa.z + ua.w * xa.w
       + ub.x * xb.x + ub.y * xb.y + ub.z * xb.z + ub.w * xb.w;
    xa = n1[l]; xb = n1[l + 16];
    a1 = ua.x * xa.x + ua.y * xa.y + ua.z * xa.z + ua.w * xa.w
       + ub.x * xb.x + ub.y * xb.y + ub.z * xb.z + ub.w * xb.w;
    xa = n2[l]; xb = n2[l + 16];
    a2 = ua.x * xa.x + ua.y * xa.y + ua.z * xa.z + ua.w * xa.w
       + ub.x * xb.x + ub.y * xb.y + ub.z * xb.z + ub.w * xb.w;
    xa = n3[l]; xb = n3[l + 16];
    a3 = ua.x * xa.x + ua.y * xa.y + ua.z * xa.z + ua.w * xa.w
       + ub.x * xb.x + ub.y * xb.y + ub.z * xb.z + ub.w * xb.w;
    xa = n4[l]; xb = n4[l + 16];
    a4 = ua.x * xa.x + ua.y * xa.y + ua.z * xa.z + ua.w * xa.w
       + ub.x * xb.x + ub.y * xb.y + ub.z * xb.z + ub.w * xb.w;
  }
  #pragma unroll
  for (int off = 8; off > 0; off >>= 1) {
    ap += __shfl_xor(ap, off, 64);
    a0 += __shfl_xor(a0, off, 64);
    a1 += __shfl_xor(a1, off, 64);
    a2 += __shfl_xor(a2, off, 64);
    a3 += __shfl_xor(a3, off, 64);
    a4 += __shfl_xor(a4, off, 64);
  }
  if (l == 0) {
    float loss;
    ap = fminf(fmaxf(ap, -10.f), 10.f); loss  = log1pf(expf(-ap));
    a0 = fminf(fmaxf(a0, -10.f), 10.f); loss += log1pf(expf(a0));
    a1 = fminf(fmaxf(a1, -10.f), 10.f); loss += log1pf(expf(a1));
    a2 = fminf(fmaxf(a2, -10.f), 10.f); loss += log1pf(expf(a2));
    a3 = fminf(fmaxf(a3, -10.f), 10.f); loss += log1pf(expf(a3));
    a4 = fminf(fmaxf(a4, -10.f), 10.f); loss += log1pf(expf(a4));
    red[g] = loss;
  }
  __syncthreads();
  if (threadIdx.x == 0) {
    float t = 0.f;
    #pragma unroll
    for (int k = 0; k < 16; k++) t += red[k];
    partial[blockIdx.x] = t;
  }
}

__global__ __launch_bounds__(256) void reduce_loss(const float* __restrict__ partial, float* __restrict__ out) {
  __shared__ float red[256];
  float s = 0.f;
  for (int i = threadIdx.x; i < 6250; i += 256) s += partial[i];
  red[threadIdx.x] = s;
  __syncthreads();
  for (int off = 128; off > 0; off >>= 1) {
    if (threadIdx.x < off) red[threadIdx.x] += red[threadIdx.x + off];
    __syncthreads();
  }
  if (threadIdx.x == 0) out[0] = red[0] / (float)BATCH;
}

// ---------------- edge scores: wave per edge ----------------
__global__ __launch_bounds__(256) void edge_scores(const float* __restrict__ h,
    const int* __restrict__ ps, const int* __restrict__ pd,
    const int* __restrict__ ns, const int* __restrict__ nd,
    float* __restrict__ out) {
  int w = threadIdx.x >> 6, lane = threadIdx.x & 63;
  int e = blockIdx.x * 4 + w;
  if (e >= 2 * EPE) return;
  int src, dst;
  if (e < EPE) { src = ps[e]; dst = pd[e]; }
  else         { src = ns[e - EPE]; dst = nd[e - EPE]; }
  const float4* hs = (const float4*)(h + (size_t)src * 256);
  const float4* hd = (const float4*)(h + (size_t)(1000 + dst) * 256);
  float4 a = hs[lane], b = hd[lane];
  float p = a.x * b.x + a.y * b.y + a.z * b.z + a.w * b.w;
  #pragma unroll
  for (int off = 32; off > 0; off >>= 1) p += __shfl_xor(p, off, 64);
  if (lane == 0) out[1 + e] = p;
}

// ---------------- launch ----------------
extern "C" void kernel_launch(void* const* d_in, const int* in_sizes, int n_in,
                              void* d_out, int out_size, void* d_ws, size_t ws_size,
                              hipStream_t stream) {
  const float* node_embed    = (const float*)d_in[0];
  const float* context_embed = (const float*)d_in[1];
  const float* adj           = (const float*)d_in[2];
  const float* W1            = (const float*)d_in[3];
  const float* b1            = (const float*)d_in[4];
  const float* W2            = (const float*)d_in[5];
  const float* b2            = (const float*)d_in[6];
  const int* pos_u   = (const int*)d_in[7];
  const int* pos_v   = (const int*)d_in[8];
  const int* neg_v   = (const int*)d_in[9];
  const int* pos_src = (const int*)d_in[10];
  const int* pos_dst = (const int*)d_in[11];
  const int* neg_src = (const int*)d_in[12];
  const int* neg_dst = (const int*)d_in[13];
  float* out = (float*)d_out;

  char* ws = (char*)d_ws;
  u16*   Ap    = (u16*)(ws + OFF_AP);
  u16*   ATp   = (u16*)(ws + OFF_ATP);
  u16*   Sp    = (u16*)(ws + OFF_SP);
  float* G     = (float*)(ws + OFF_G);
  u16*   Gns   = (u16*)(ws + OFF_GNS);
  u16*   Gndt  = (u16*)(ws + OFF_GNDT);
  u16*   W1At  = (u16*)(ws + OFF_W1AT);
  u16*   W1Bt  = (u16*)(ws + OFF_W1BT);
  u16*   w2t   = (u16*)(ws + OFF_W2T);
  u16*   hid   = (u16*)(ws + OFF_HID);
  float* degs  = (float*)(ws + OFF_DEGS);
  float* degd  = (float*)(ws + OFF_DEGD);
  float* cn    = (float*)(ws + OFF_CN);
  float* part  = (float*)(ws + OFF_PART);
  float* h     = (float*)(ws + OFF_H);

  // packs
  pack_A<<<4096, 256, 0, stream>>>(adj, Ap);
  transpose_packA<<<dim3(16, 16), 256, 0, stream>>>(adj, ATp);
  pack_w1t<<<1024, 256, 0, stream>>>(W1, W1At, W1Bt);
  pack_w2t<<<128, 256, 0, stream>>>(W2, w2t);
  copy_nodeh<<<1000, 256, 0, stream>>>(node_embed, h);

  // degrees: degd[j] = colsum(A)[j], degs[i] = colsum(A^T)[i] = rowsum(A)[i]
  colsum16<<<32, 256, 0, stream>>>(Ap, degd);
  colsum16<<<32, 256, 0, stream>>>(ATp, degs);

  // S = A A^T  (exact integers in bf16)
  gemm_bt<0><<<dim3(8, 8), 256, 0, stream>>>(Ap, Ap, 1024, 1024, 1024,
                                             Sp, 1024, nullptr, nullptr, nullptr, nullptr, nullptr, nullptr);
  // G = (S @ A) * A / (degs degd^T)
  gemm_bt<1><<<dim3(8, 8), 256, 0, stream>>>(Sp, ATp, 1024, 1024, 1024,
                                             nullptr, 0, G, Ap, degs, degd, nullptr, nullptr);
  // normalize
  rnorm_scale<<<1024, 256, 0, stream>>>(G, Gns);
  cnorm<<<32, 256, 0, stream>>>(G, cn);
  transpose_scale<<<dim3(16, 16), 256, 0, stream>>>(G, cn, Gndt);

  // hidden = tanh(gamma_hat @ W1 + b1), src and dst halves
  gemm_bt<2><<<dim3(8, 2), 256, 0, stream>>>(Gns, W1Bt, 1024, 1024, 1024,
                                             hid, 256, nullptr, nullptr, nullptr, nullptr, b1, nullptr);
  gemm_bt<2><<<dim3(8, 2), 256, 0, stream>>>(Gndt, W1At, 1024, 1024, 1024,
                                             hid + (size_t)1024 * 256, 256, nullptr, nullptr, nullptr, nullptr, b1, nullptr);
  // h[:,128:] = hid @ W2 + b2
  gemm_bt<3><<<dim3(16, 1), 256, 0, stream>>>(hid, w2t, 256, 256, 256,
                                              nullptr, 0, nullptr, nullptr, nullptr, nullptr, b2, h);

  // skipgram loss
  skipgram<<<6250, 256, 0, stream>>>(node_embed, context_embed, pos_u, pos_v, neg_v, part);
  reduce_loss<<<1, 256, 0, stream>>>(part, out);

  // edge scores
  edge_scores<<<100000, 256, 0, stream>>>(h, pos_src, pos_dst, neg_src, neg_dst, out);
}

// Round 3
// 190.886 us; speedup vs baseline: 1.9910x; 1.9910x over previous
//
#include <hip/hip_runtime.h>
#include <hip/hip_bf16.h>

typedef __attribute__((ext_vector_type(8))) short bf16x8;
typedef __attribute__((ext_vector_type(4))) float f32x4;
typedef unsigned short u16;

#define BATCH 100000
#define EPE 200000

// ---- workspace layout (bytes) ----
#define OFF_AP    ((size_t)0)          // u16 [1024*1024]
#define OFF_ATP   ((size_t)2097152)    // u16 [1024*1024]
#define OFF_SP    ((size_t)4194304)    // u16 [1024*1024]
#define OFF_G     ((size_t)6291456)    // f32 [1024*1024]
#define OFF_GNS   ((size_t)10485760)   // u16 [1024*1024]
#define OFF_GNDT  ((size_t)12582912)   // u16 [1024*1024]
#define OFF_W1AT  ((size_t)14680064)   // u16 [256*1024]
#define OFF_W1BT  ((size_t)15204352)   // u16 [256*1024]
#define OFF_W2T   ((size_t)15728640)   // u16 [128*256]
#define OFF_HID   ((size_t)15794176)   // u16 [2048*256]
#define OFF_NEP   ((size_t)16842752)   // u16 [2048*128]
#define OFF_CEP   ((size_t)17367040)   // u16 [2048*128]
#define OFF_HSRC  ((size_t)17891328)   // u16 [1024*256]
#define OFF_HDST  ((size_t)18415616)   // u16 [1024*256]
#define OFF_T2    ((size_t)18939904)   // f32 [1024*1024]
#define OFF_DEGS  ((size_t)23134208)   // f32 [1024]
#define OFF_DEGD  ((size_t)23138304)   // f32 [1024]
#define OFF_CN    ((size_t)23142400)   // f32 [1024]
#define OFF_PART  ((size_t)23146496)   // f32 [512]
#define OFF_T1    ((size_t)23150592)   // u16 [2048*2048]  (ends ~30.1 MB)

__device__ __forceinline__ u16 f2b(float f) {
  union { float f; unsigned u; } v; v.f = f;
  unsigned r = v.u + 0x7fffu + ((v.u >> 16) & 1u);
  return (u16)(r >> 16);
}
__device__ __forceinline__ float b2f(u16 h) {
  union { unsigned u; float f; } v; v.u = ((unsigned)h) << 16;
  return v.f;
}

#define AS1C(p) ((const __attribute__((address_space(1))) void*)(p))
#define AS3(p)  ((__attribute__((address_space(3))) void*)(p))

// ---------------- pack adj block + transpose (64x64 LDS tiles) ----------------
__global__ __launch_bounds__(256) void pack_adj_t(const float* __restrict__ adj,
                                                  u16* __restrict__ Ap, u16* __restrict__ ATp) {
  __shared__ u16 tile[64][65];
  int tr = blockIdx.x, tc = blockIdx.y;
  int tx = threadIdx.x & 63, ty = threadIdx.x >> 6;
  #pragma unroll
  for (int p = 0; p < 16; p++) {
    int r = p * 4 + ty;
    int gr = tr * 64 + r, gc = tc * 64 + tx;
    float v = (gr < 1000 && gc < 1000) ? adj[(size_t)gr * 2000 + 1000 + gc] : 0.f;
    u16 b = f2b(v);
    Ap[(size_t)gr * 1024 + gc] = b;
    tile[r][tx] = b;
  }
  __syncthreads();
  #pragma unroll
  for (int p = 0; p < 16; p++) {
    int r = p * 4 + ty;
    ATp[(size_t)(tc * 64 + r) * 1024 + tr * 64 + tx] = tile[tx][r];
  }
}

// ---------------- degrees: blocks 0-31 colsum(Ap)->degd, 32-63 colsum(ATp)->degs ----
__global__ __launch_bounds__(256) void degrees(const u16* __restrict__ Ap, const u16* __restrict__ ATp,
                                               float* __restrict__ degd, float* __restrict__ degs) {
  __shared__ float red[8][32];
  int b = blockIdx.x;
  const u16* M = (b < 32) ? Ap : ATp;
  float* o = (b < 32) ? degd : degs;
  int cx = threadIdx.x & 31, ry = threadIdx.x >> 5;
  int j = (b & 31) * 32 + cx;
  float s = 0.f;
  for (int r = ry; r < 1024; r += 8) s += b2f(M[(size_t)r * 1024 + j]);
  red[ry][cx] = s;
  __syncthreads();
  if (ry == 0) {
    float t = 0.f;
    #pragma unroll
    for (int k = 0; k < 8; k++) t += red[k][cx];
    o[j] = t;
  }
}

// ---------------- fused misc packs ----------------
// blocks [0,1024): W1At/W1Bt; [1024,1152): w2t; [1152,2176): nep/cep/hsrcp/hdstp cols 0..127
__global__ __launch_bounds__(256) void pack_misc(const float* __restrict__ W1, const float* __restrict__ W2,
    const float* __restrict__ ne, const float* __restrict__ ce,
    u16* __restrict__ W1At, u16* __restrict__ W1Bt, u16* __restrict__ w2t,
    u16* __restrict__ nep, u16* __restrict__ cep,
    u16* __restrict__ hsrcp, u16* __restrict__ hdstp) {
  int b = blockIdx.x;
  if (b < 1024) {
    int idx = b * 256 + threadIdx.x;          // 256*1024
    int hh = idx >> 10, j = idx & 1023;
    float a = (j < 1000) ? W1[(size_t)j * 256 + hh] : 0.f;
    float bb = (j < 1000) ? W1[(size_t)(1000 + j) * 256 + hh] : 0.f;
    W1At[idx] = f2b(a);
    W1Bt[idx] = f2b(bb);
  } else if (b < 1152) {
    int idx = (b - 1024) * 256 + threadIdx.x; // 128*256
    int d = idx >> 8, k = idx & 255;
    w2t[idx] = f2b(W2[(size_t)k * 128 + d]);
  } else {
    int idx = (b - 1152) * 256 + threadIdx.x; // 2048*128
    int i = idx >> 7, d = idx & 127;
    float nv = (i < 2000) ? ne[(size_t)i * 128 + d] : 0.f;
    float cv = (i < 2000) ? ce[(size_t)i * 128 + d] : 0.f;
    u16 nb = f2b(nv);
    nep[idx] = nb;
    cep[idx] = f2b(cv);
    if (i < 1000)                 hsrcp[(size_t)i * 256 + d] = nb;
    else if (i < 1024)            hsrcp[(size_t)i * 256 + d] = 0;
    if (i >= 1000 && i < 2000)    hdstp[(size_t)(i - 1000) * 256 + d] = nb;
    else if (i >= 2000 && i < 2024) hdstp[(size_t)(i - 1000) * 256 + d] = 0;
  }
}

// ---------------- generalized bf16 MFMA GEMM: C = A * BT^T ----------------
// BM = 32*MR, BN = 32*NR, BK = 64, 4 waves (2x2), wave tile = MR*16 x NR*16.
// EPI 0: outb[row*ldo+col] = bf16(C)
// EPI 1: outf = C * apack / (degs[r]*degd[c])  (f32, ld 1024)
// EPI 2: outb[(z*1024+row)*256+col] = bf16(tanh(C + bias[col]))
// EPI 3: h pack: bf16(C + bias[col]) -> hsrcp/hdstp cols 128..255
// EPI 4: outf[row*ldo+col] = C (f32)
template <int EPI, int MR, int NR>
__global__ __launch_bounds__(256) void gemm_bt(
    const u16* __restrict__ A, const u16* __restrict__ BT,
    const u16* __restrict__ A2, const u16* __restrict__ BT2,
    int K, int lda, int ldbt,
    u16* __restrict__ outb, int ldo,
    float* __restrict__ outf,
    const u16* __restrict__ apack,
    const float* __restrict__ degs, const float* __restrict__ degd,
    const float* __restrict__ bias,
    u16* __restrict__ hsrcp, u16* __restrict__ hdstp)
{
  constexpr int BMt = 32 * MR, BNt = 32 * NR;
  __shared__ u16 As[BMt * 64];
  __shared__ u16 Bs[BNt * 64];
  const int t = threadIdx.x;
  const int w = t >> 6, lane = t & 63;
  const int brow = blockIdx.x * BMt, bcol = blockIdx.y * BNt;
  const int wr = w >> 1, wc = w & 1;
  const int r16 = lane & 15, kg = lane >> 4;
  const u16* Au = (blockIdx.z == 0) ? A : A2;
  const u16* Bu = (blockIdx.z == 0) ? BT : BT2;

  f32x4 acc[MR][NR];
  #pragma unroll
  for (int m = 0; m < MR; m++)
    #pragma unroll
    for (int n = 0; n < NR; n++) {
      f32x4 z = {0.f, 0.f, 0.f, 0.f};
      acc[m][n] = z;
    }

  for (int k0 = 0; k0 < K; k0 += 64) {
    #pragma unroll
    for (int it = 0; it < MR; ++it) {
      int chunk = it * 256 + t;
      int row = chunk >> 3, cc = chunk & 7;
      const u16* ga = Au + (size_t)(brow + row) * lda + k0 + cc * 8;
      __builtin_amdgcn_global_load_lds(AS1C(ga), AS3(As + (size_t)(it * 256 + w * 64) * 8), 16, 0, 0);
    }
    #pragma unroll
    for (int it = 0; it < NR; ++it) {
      int chunk = it * 256 + t;
      int row = chunk >> 3, cc = chunk & 7;
      const u16* gb = Bu + (size_t)(bcol + row) * ldbt + k0 + cc * 8;
      __builtin_amdgcn_global_load_lds(AS1C(gb), AS3(Bs + (size_t)(it * 256 + w * 64) * 8), 16, 0, 0);
    }
    __syncthreads();
    #pragma unroll
    for (int kk = 0; kk < 2; ++kk) {
      bf16x8 af[MR], bfr[NR];
      #pragma unroll
      for (int m = 0; m < MR; m++)
        af[m] = *(const bf16x8*)&As[(wr * (MR * 16) + m * 16 + r16) * 64 + kk * 32 + kg * 8];
      #pragma unroll
      for (int n = 0; n < NR; n++)
        bfr[n] = *(const bf16x8*)&Bs[(wc * (NR * 16) + n * 16 + r16) * 64 + kk * 32 + kg * 8];
      #pragma unroll
      for (int m = 0; m < MR; m++)
        #pragma unroll
        for (int n = 0; n < NR; n++)
          acc[m][n] = __builtin_amdgcn_mfma_f32_16x16x32_bf16(af[m], bfr[n], acc[m][n], 0, 0, 0);
    }
    __syncthreads();
  }

  #pragma unroll
  for (int m = 0; m < MR; m++) {
    #pragma unroll
    for (int n = 0; n < NR; n++) {
      #pragma unroll
      for (int j = 0; j < 4; j++) {
        int row = brow + wr * (MR * 16) + m * 16 + kg * 4 + j;
        int col = bcol + wc * (NR * 16) + n * 16 + r16;
        float val = acc[m][n][j];
        if constexpr (EPI == 0) {
          outb[(size_t)row * ldo + col] = f2b(val);
        } else if constexpr (EPI == 1) {
          float a = b2f(apack[(size_t)row * 1024 + col]);
          float p2 = degs[row] * degd[col];
          float g = (p2 > 0.f) ? (val * a) / p2 : 0.f;
          outf[(size_t)row * 1024 + col] = g;
        } else if constexpr (EPI == 2) {
          outb[(size_t)(blockIdx.z * 1024 + row) * 256 + col] = f2b(tanhf(val + bias[col]));
        } else if constexpr (EPI == 3) {
          u16 hv = f2b(val + bias[col]);
          if (row < 1024) hsrcp[(size_t)row * 256 + 128 + col] = hv;
          else            hdstp[(size_t)(row - 1024) * 256 + 128 + col] = hv;
        } else {
          outf[(size_t)row * ldo + col] = val;
        }
      }
    }
  }
}

// ---------------- gamma normalization ----------------
__global__ __launch_bounds__(256) void rnorm_scale(const float* __restrict__ G, u16* __restrict__ Gns) {
  __shared__ float red[256];
  int i = blockIdx.x;
  const float* row = G + (size_t)i * 1024;
  float v[4];
  float s = 0.f;
  #pragma unroll
  for (int c = 0; c < 4; c++) { v[c] = row[threadIdx.x + 256 * c]; s += v[c] * v[c]; }
  red[threadIdx.x] = s;
  __syncthreads();
  for (int off = 128; off > 0; off >>= 1) {
    if (threadIdx.x < off) red[threadIdx.x] += red[threadIdx.x + off];
    __syncthreads();
  }
  float inv = 1.0f / fmaxf(sqrtf(red[0]), 1e-12f);
  u16* orow = Gns + (size_t)i * 1024;
  #pragma unroll
  for (int c = 0; c < 4; c++) orow[threadIdx.x + 256 * c] = f2b(v[c] * inv);
}

__global__ __launch_bounds__(256) void cnorm(const float* __restrict__ G, float* __restrict__ cn) {
  __shared__ float red[8][32];
  int cx = threadIdx.x & 31, ry = threadIdx.x >> 5;
  int j = blockIdx.x * 32 + cx;
  float s = 0.f;
  for (int r = ry; r < 1024; r += 8) { float g = G[(size_t)r * 1024 + j]; s += g * g; }
  red[ry][cx] = s;
  __syncthreads();
  if (ry == 0) {
    float t = 0.f;
    #pragma unroll
    for (int k = 0; k < 8; k++) t += red[k][cx];
    cn[j] = sqrtf(t);
  }
}

__global__ __launch_bounds__(256) void transpose_scale(const float* __restrict__ G,
                                                       const float* __restrict__ cn,
                                                       u16* __restrict__ Gndt) {
  __shared__ float tile[64][65];
  int tr = blockIdx.x, tc = blockIdx.y;
  int tx = threadIdx.x & 63, ty = threadIdx.x >> 6;
  #pragma unroll
  for (int p = 0; p < 16; p++) {
    int r = p * 4 + ty;
    tile[r][tx] = G[(size_t)(tr * 64 + r) * 1024 + tc * 64 + tx];
  }
  __syncthreads();
  #pragma unroll
  for (int p = 0; p < 16; p++) {
    int r = p * 4 + ty;
    int oc = tc * 64 + r;
    float inv = 1.0f / fmaxf(cn[oc], 1e-12f);
    Gndt[(size_t)oc * 1024 + tr * 64 + tx] = f2b(tile[tx][r] * inv);
  }
}

// ---------------- skipgram gather from T1 ----------------
__global__ __launch_bounds__(256) void skipgram_gather(const u16* __restrict__ T1,
    const int* __restrict__ pu, const int* __restrict__ pv, const int* __restrict__ nv,
    float* __restrict__ partial) {
  __shared__ float red[256];
  int s = blockIdx.x * 256 + threadIdx.x;
  float loss = 0.f;
  if (s < BATCH) {
    const u16* trow = T1 + (size_t)pu[s] * 2048;
    const int* nvb = nv + (size_t)s * 5;
    float ap = b2f(trow[pv[s]]);
    ap = fminf(fmaxf(ap, -10.f), 10.f); loss = log1pf(expf(-ap));
    #pragma unroll
    for (int k = 0; k < 5; k++) {
      float a = b2f(trow[nvb[k]]);
      a = fminf(fmaxf(a, -10.f), 10.f);
      loss += log1pf(expf(a));
    }
  }
  red[threadIdx.x] = loss;
  __syncthreads();
  for (int off = 128; off > 0; off >>= 1) {
    if (threadIdx.x < off) red[threadIdx.x] += red[threadIdx.x + off];
    __syncthreads();
  }
  if (threadIdx.x == 0) partial[blockIdx.x] = red[0];
}

__global__ __launch_bounds__(256) void reduce_loss(const float* __restrict__ partial, float* __restrict__ out) {
  __shared__ float red[256];
  float s = 0.f;
  for (int i = threadIdx.x; i < 391; i += 256) s += partial[i];
  red[threadIdx.x] = s;
  __syncthreads();
  for (int off = 128; off > 0; off >>= 1) {
    if (threadIdx.x < off) red[threadIdx.x] += red[threadIdx.x + off];
    __syncthreads();
  }
  if (threadIdx.x == 0) out[0] = red[0] / (float)BATCH;
}

// ---------------- edge gather from T2 ----------------
__global__ __launch_bounds__(256) void edge_gather(const float* __restrict__ T2,
    const int* __restrict__ ps, const int* __restrict__ pd,
    const int* __restrict__ ns, const int* __restrict__ nd,
    float* __restrict__ out) {
  int e = blockIdx.x * 256 + threadIdx.x;
  if (e >= 2 * EPE) return;
  int src, dst;
  if (e < EPE) { src = ps[e]; dst = pd[e]; }
  else         { src = ns[e - EPE]; dst = nd[e - EPE]; }
  out[1 + e] = T2[(size_t)src * 1024 + dst];
}

// ---------------- launch ----------------
extern "C" void kernel_launch(void* const* d_in, const int* in_sizes, int n_in,
                              void* d_out, int out_size, void* d_ws, size_t ws_size,
                              hipStream_t stream) {
  const float* node_embed    = (const float*)d_in[0];
  const float* context_embed = (const float*)d_in[1];
  const float* adj           = (const float*)d_in[2];
  const float* W1            = (const float*)d_in[3];
  const float* b1            = (const float*)d_in[4];
  const float* W2            = (const float*)d_in[5];
  const float* b2            = (const float*)d_in[6];
  const int* pos_u   = (const int*)d_in[7];
  const int* pos_v   = (const int*)d_in[8];
  const int* neg_v   = (const int*)d_in[9];
  const int* pos_src = (const int*)d_in[10];
  const int* pos_dst = (const int*)d_in[11];
  const int* neg_src = (const int*)d_in[12];
  const int* neg_dst = (const int*)d_in[13];
  float* out = (float*)d_out;

  char* ws = (char*)d_ws;
  u16*   Ap    = (u16*)(ws + OFF_AP);
  u16*   ATp   = (u16*)(ws + OFF_ATP);
  u16*   Sp    = (u16*)(ws + OFF_SP);
  float* G     = (float*)(ws + OFF_G);
  u16*   Gns   = (u16*)(ws + OFF_GNS);
  u16*   Gndt  = (u16*)(ws + OFF_GNDT);
  u16*   W1At  = (u16*)(ws + OFF_W1AT);
  u16*   W1Bt  = (u16*)(ws + OFF_W1BT);
  u16*   w2t   = (u16*)(ws + OFF_W2T);
  u16*   hid   = (u16*)(ws + OFF_HID);
  u16*   nep   = (u16*)(ws + OFF_NEP);
  u16*   cep   = (u16*)(ws + OFF_CEP);
  u16*   hsrcp = (u16*)(ws + OFF_HSRC);
  u16*   hdstp = (u16*)(ws + OFF_HDST);
  float* T2    = (float*)(ws + OFF_T2);
  float* degs  = (float*)(ws + OFF_DEGS);
  float* degd  = (float*)(ws + OFF_DEGD);
  float* cn    = (float*)(ws + OFF_CN);
  float* part  = (float*)(ws + OFF_PART);
  u16*   T1    = (u16*)(ws + OFF_T1);

  // packs
  pack_adj_t<<<dim3(16, 16), 256, 0, stream>>>(adj, Ap, ATp);
  pack_misc<<<2176, 256, 0, stream>>>(W1, W2, node_embed, context_embed,
                                      W1At, W1Bt, w2t, nep, cep, hsrcp, hdstp);
  degrees<<<64, 256, 0, stream>>>(Ap, ATp, degd, degs);

  // T1 = ne @ ce^T  (2048x2048, K=128) -> bf16 table
  gemm_bt<0, 4, 4><<<dim3(16, 16), 256, 0, stream>>>(nep, cep, nullptr, nullptr, 128, 128, 128,
      T1, 2048, nullptr, nullptr, nullptr, nullptr, nullptr, nullptr, nullptr);
  skipgram_gather<<<391, 256, 0, stream>>>(T1, pos_u, pos_v, neg_v, part);
  reduce_loss<<<1, 256, 0, stream>>>(part, out);

  // S = A A^T  (exact integers in bf16)
  gemm_bt<0, 2, 2><<<dim3(16, 16), 256, 0, stream>>>(Ap, Ap, nullptr, nullptr, 1024, 1024, 1024,
      Sp, 1024, nullptr, nullptr, nullptr, nullptr, nullptr, nullptr, nullptr);
  // G = (S @ A) * A / (degs degd^T)
  gemm_bt<1, 2, 2><<<dim3(16, 16), 256, 0, stream>>>(Sp, ATp, nullptr, nullptr, 1024, 1024, 1024,
      nullptr, 0, G, Ap, degs, degd, nullptr, nullptr, nullptr);
  // normalize
  rnorm_scale<<<1024, 256, 0, stream>>>(G, Gns);
  cnorm<<<32, 256, 0, stream>>>(G, cn);
  transpose_scale<<<dim3(16, 16), 256, 0, stream>>>(G, cn, Gndt);

  // hid = tanh(gamma_hat @ W1 + b1): z=0 src half (Gns @ W1Bt^T), z=1 dst half (Gndt @ W1At^T)
  gemm_bt<2, 2, 4><<<dim3(16, 2, 2), 256, 0, stream>>>(Gns, W1Bt, Gndt, W1At, 1024, 1024, 1024,
      hid, 0, nullptr, nullptr, nullptr, nullptr, b1, nullptr, nullptr);
  // h[:,128:] = hid @ W2 + b2 -> bf16 into hsrcp/hdstp cols 128..255
  gemm_bt<3, 2, 4><<<dim3(32, 1), 256, 0, stream>>>(hid, w2t, nullptr, nullptr, 256, 256, 256,
      nullptr, 0, nullptr, nullptr, nullptr, nullptr, b2, hsrcp, hdstp);

  // T2 = h_src @ h_dst^T (1024x1024, K=256) -> f32 table
  gemm_bt<4, 2, 2><<<dim3(16, 16), 256, 0, stream>>>(hsrcp, hdstp, nullptr, nullptr, 256, 256, 256,
      nullptr, 1024, T2, nullptr, nullptr, nullptr, nullptr, nullptr, nullptr);
  edge_gather<<<1563, 256, 0, stream>>>(T2, pos_src, pos_dst, neg_src, neg_dst, out);
}

// Round 4
// 113.657 us; speedup vs baseline: 3.3439x; 1.6795x over previous
//
#include <hip/hip_runtime.h>
#include <hip/hip_bf16.h>

typedef __attribute__((ext_vector_type(8))) short bf16x8;
typedef __attribute__((ext_vector_type(4))) float f32x4;
typedef unsigned short u16;

#define BATCH 100000
#define EPE 200000

// ---- workspace layout (bytes), peak ~27.3 MB ----
#define OFF_AP    ((size_t)0)          // u16 [1024*1024]
#define OFF_ATP   ((size_t)2097152)    // u16 [1024*1024]
#define OFF_SP    ((size_t)4194304)    // u16 [1024*1024]
#define OFF_T1    ((size_t)6291456)    // u16 [2048*2048] (dead after skipgram_gather)
#define OFF_G     ((size_t)6291456)    // f32 [1024*1024] (reuses T1 space)
#define OFF_GT    ((size_t)10485760)   // f32 [1024*1024]
#define OFF_GNS   ((size_t)14680064)   // u16 [1024*1024]
#define OFF_GNDT  ((size_t)16777216)   // u16 [1024*1024]
#define OFF_W1AT  ((size_t)18874368)   // u16 [256*1024]
#define OFF_W1BT  ((size_t)19398656)   // u16 [256*1024]
#define OFF_W2T   ((size_t)19922944)   // u16 [128*256]
#define OFF_HID   ((size_t)19988480)   // u16 [2048*256]
#define OFF_NEP   ((size_t)21037056)   // u16 [2048*128]
#define OFF_CEP   ((size_t)21561344)   // u16 [2048*128]
#define OFF_HSRC  ((size_t)22085632)   // u16 [1024*256]
#define OFF_HDST  ((size_t)22609920)   // u16 [1024*256]
#define OFF_T2    ((size_t)23134208)   // f32 [1024*1024]
#define OFF_DEGS  ((size_t)27328512)   // f32 [1024]
#define OFF_DEGD  ((size_t)27332608)   // f32 [1024]
#define OFF_PART  ((size_t)27336704)   // f32 [391]

__device__ __forceinline__ u16 f2b(float f) {
  union { float f; unsigned u; } v; v.f = f;
  unsigned r = v.u + 0x7fffu + ((v.u >> 16) & 1u);
  return (u16)(r >> 16);
}
__device__ __forceinline__ float b2f(u16 h) {
  union { unsigned u; float f; } v; v.u = ((unsigned)h) << 16;
  return v.f;
}

#define AS1C(p) ((const __attribute__((address_space(1))) void*)(p))
#define AS3(p)  ((__attribute__((address_space(3))) void*)(p))

// ---------------- fused prep: all packs + degrees from raw adj ----------------
// blocks: [0,256) adj tile pack+transpose; [256,1280) W1; [1280,1408) W2;
//         [1408,2432) ne/ce/h-halves; [2432,2464) degd; [2464,2496) degs
__global__ __launch_bounds__(256) void prep(const float* __restrict__ adj,
    const float* __restrict__ W1, const float* __restrict__ W2,
    const float* __restrict__ ne, const float* __restrict__ ce,
    u16* __restrict__ Ap, u16* __restrict__ ATp,
    u16* __restrict__ W1At, u16* __restrict__ W1Bt, u16* __restrict__ w2t,
    u16* __restrict__ nep, u16* __restrict__ cep,
    u16* __restrict__ hsrcp, u16* __restrict__ hdstp,
    float* __restrict__ degd, float* __restrict__ degs) {
  __shared__ u16 tile[64][65];
  __shared__ float redf[256];
  int b = blockIdx.x;
  int t = threadIdx.x;
  if (b < 256) {
    int tr = b >> 4, tc = b & 15;
    int tx = t & 63, ty = t >> 6;
    #pragma unroll
    for (int p = 0; p < 16; p++) {
      int r = p * 4 + ty;
      int gr = tr * 64 + r, gc = tc * 64 + tx;
      float v = (gr < 1000 && gc < 1000) ? adj[(size_t)gr * 2000 + 1000 + gc] : 0.f;
      u16 bb = f2b(v);
      Ap[(size_t)gr * 1024 + gc] = bb;
      tile[r][tx] = bb;
    }
    __syncthreads();
    #pragma unroll
    for (int p = 0; p < 16; p++) {
      int r = p * 4 + ty;
      ATp[(size_t)(tc * 64 + r) * 1024 + tr * 64 + tx] = tile[tx][r];
    }
  } else if (b < 1280) {
    int idx = (b - 256) * 256 + t;            // 256*1024
    int hh = idx >> 10, j = idx & 1023;
    float a  = (j < 1000) ? W1[(size_t)j * 256 + hh] : 0.f;
    float bb = (j < 1000) ? W1[(size_t)(1000 + j) * 256 + hh] : 0.f;
    W1At[idx] = f2b(a);
    W1Bt[idx] = f2b(bb);
  } else if (b < 1408) {
    int idx = (b - 1280) * 256 + t;           // 128*256
    int d = idx >> 8, k = idx & 255;
    w2t[idx] = f2b(W2[(size_t)k * 128 + d]);
  } else if (b < 2432) {
    int idx = (b - 1408) * 256 + t;           // 2048*128
    int i = idx >> 7, d = idx & 127;
    float nv = (i < 2000) ? ne[(size_t)i * 128 + d] : 0.f;
    float cv = (i < 2000) ? ce[(size_t)i * 128 + d] : 0.f;
    u16 nb = f2b(nv);
    nep[idx] = nb;
    cep[idx] = f2b(cv);
    if (i < 1000)                   hsrcp[(size_t)i * 256 + d] = nb;
    else if (i < 1024)              hsrcp[(size_t)i * 256 + d] = 0;
    if (i >= 1000 && i < 2000)      hdstp[(size_t)(i - 1000) * 256 + d] = nb;
    else if (i >= 2000 && i < 2024) hdstp[(size_t)(i - 1000) * 256 + d] = 0;
  } else if (b < 2464) {
    // degd[j] = colsum of A
    int jb = b - 2432;
    int cx = t & 31, ry = t >> 5;
    int j = jb * 32 + cx;
    float s = 0.f;
    if (j < 1000)
      for (int i = ry; i < 1000; i += 8) s += adj[(size_t)i * 2000 + 1000 + j];
    redf[t] = s;
    __syncthreads();
    if (ry == 0) {
      float tot = 0.f;
      #pragma unroll
      for (int k = 0; k < 8; k++) tot += redf[k * 32 + cx];
      degd[j] = (j < 1000) ? tot : 0.f;
    }
  } else {
    // degs[i] = rowsum of A
    int ib = b - 2464;
    int r = t >> 3, c8 = t & 7;
    int i = ib * 32 + r;
    float s = 0.f;
    if (i < 1000)
      for (int k = c8; k < 1000; k += 8) s += adj[(size_t)i * 2000 + 1000 + k];
    redf[t] = s;
    __syncthreads();
    if (c8 == 0) {
      float tot = 0.f;
      #pragma unroll
      for (int k = 0; k < 8; k++) tot += redf[r * 8 + k];
      degs[i] = (i < 1000) ? tot : 0.f;
    }
  }
}

// ---------------- generalized bf16 MFMA GEMM, 2-phase double-buffered ----------------
// C = A * BT^T. BM=32*MR, BN=32*NR, BK=64, 4 waves (2x2).
// EPI 0: outb bf16 (ldo)
// EPI 1: g = C*apack/(degs[r]*degd[c]); G[r*1024+c] = g; Gt[c*1024+r] = g
// EPI 2: hid: bf16(tanh(C + bias[col])) at [(z*1024+row)*256+col]
// EPI 3: bf16(C + bias[col]) -> hsrcp/hdstp cols 128..255 (rows 0..1023 src, 1024.. dst)
// EPI 4: outf f32 (ldo)
template <int EPI, int MR, int NR>
__global__ __launch_bounds__(256) void gemm_bt(
    const u16* __restrict__ A, const u16* __restrict__ BT,
    const u16* __restrict__ A2, const u16* __restrict__ BT2,
    int K, int lda, int ldbt,
    u16* __restrict__ outb, int ldo,
    float* __restrict__ outf,
    const u16* __restrict__ apack,
    const float* __restrict__ degs, const float* __restrict__ degd,
    const float* __restrict__ bias,
    u16* __restrict__ hsrcp, u16* __restrict__ hdstp,
    float* __restrict__ outf2)
{
  constexpr int BMt = 32 * MR, BNt = 32 * NR;
  __shared__ u16 As[2][BMt * 64];
  __shared__ u16 Bs[2][BNt * 64];
  const int t = threadIdx.x;
  const int w = t >> 6, lane = t & 63;
  const int brow = blockIdx.x * BMt, bcol = blockIdx.y * BNt;
  const int wr = w >> 1, wc = w & 1;
  const int r16 = lane & 15, kg = lane >> 4;
  const u16* Au = (blockIdx.z == 0) ? A : A2;
  const u16* Bu = (blockIdx.z == 0) ? BT : BT2;

  f32x4 acc[MR][NR];
  #pragma unroll
  for (int m = 0; m < MR; m++)
    #pragma unroll
    for (int n = 0; n < NR; n++) {
      f32x4 z = {0.f, 0.f, 0.f, 0.f};
      acc[m][n] = z;
    }

  auto stage = [&](int buf, int k0) {
    #pragma unroll
    for (int it = 0; it < MR; ++it) {
      int chunk = it * 256 + t;
      const u16* ga = Au + (size_t)(brow + (chunk >> 3)) * lda + k0 + (chunk & 7) * 8;
      __builtin_amdgcn_global_load_lds(AS1C(ga), AS3(As[buf] + (size_t)chunk * 8), 16, 0, 0);
    }
    #pragma unroll
    for (int it = 0; it < NR; ++it) {
      int chunk = it * 256 + t;
      const u16* gb = Bu + (size_t)(bcol + (chunk >> 3)) * ldbt + k0 + (chunk & 7) * 8;
      __builtin_amdgcn_global_load_lds(AS1C(gb), AS3(Bs[buf] + (size_t)chunk * 8), 16, 0, 0);
    }
  };

  const int nst = K >> 6;
  stage(0, 0);
  int cur = 0;
  for (int s = 0; s < nst; ++s) {
    __syncthreads();                       // drains vmcnt+lgkm: buf[cur] ready, prev reads done
    if (s + 1 < nst) stage(cur ^ 1, (s + 1) << 6);
    const u16* Asc = As[cur];
    const u16* Bsc = Bs[cur];
    #pragma unroll
    for (int kk = 0; kk < 2; ++kk) {
      bf16x8 af[MR], bfr[NR];
      #pragma unroll
      for (int m = 0; m < MR; m++)
        af[m] = *(const bf16x8*)&Asc[(wr * (MR * 16) + m * 16 + r16) * 64 + kk * 32 + kg * 8];
      #pragma unroll
      for (int n = 0; n < NR; n++)
        bfr[n] = *(const bf16x8*)&Bsc[(wc * (NR * 16) + n * 16 + r16) * 64 + kk * 32 + kg * 8];
      #pragma unroll
      for (int m = 0; m < MR; m++)
        #pragma unroll
        for (int n = 0; n < NR; n++)
          acc[m][n] = __builtin_amdgcn_mfma_f32_16x16x32_bf16(af[m], bfr[n], acc[m][n], 0, 0, 0);
    }
    cur ^= 1;
  }

  #pragma unroll
  for (int m = 0; m < MR; m++) {
    #pragma unroll
    for (int n = 0; n < NR; n++) {
      #pragma unroll
      for (int j = 0; j < 4; j++) {
        int row = brow + wr * (MR * 16) + m * 16 + kg * 4 + j;
        int col = bcol + wc * (NR * 16) + n * 16 + r16;
        float val = acc[m][n][j];
        if constexpr (EPI == 0) {
          outb[(size_t)row * ldo + col] = f2b(val);
        } else if constexpr (EPI == 1) {
          float a = b2f(apack[(size_t)row * 1024 + col]);
          float p2 = degs[row] * degd[col];
          float g = (p2 > 0.f) ? (val * a) / p2 : 0.f;
          outf[(size_t)row * 1024 + col] = g;
          outf2[(size_t)col * 1024 + row] = g;
        } else if constexpr (EPI == 2) {
          outb[(size_t)(blockIdx.z * 1024 + row) * 256 + col] = f2b(tanhf(val + bias[col]));
        } else if constexpr (EPI == 3) {
          u16 hv = f2b(val + bias[col]);
          if (row < 1024) hsrcp[(size_t)row * 256 + 128 + col] = hv;
          else            hdstp[(size_t)(row - 1024) * 256 + 128 + col] = hv;
        } else {
          outf[(size_t)row * ldo + col] = val;
        }
      }
    }
  }
}

// ---------------- fused norms: blocks [0,1024) rows of G -> Gns; [1024,2048) rows of Gt -> Gndt
__global__ __launch_bounds__(256) void normk(const float* __restrict__ G, const float* __restrict__ Gt,
                                             u16* __restrict__ Gns, u16* __restrict__ Gndt) {
  __shared__ float red[256];
  int b = blockIdx.x;
  const float* src = (b < 1024) ? (G + (size_t)b * 1024) : (Gt + (size_t)(b - 1024) * 1024);
  u16* dst = (b < 1024) ? (Gns + (size_t)b * 1024) : (Gndt + (size_t)(b - 1024) * 1024);
  float v[4];
  float s = 0.f;
  #pragma unroll
  for (int c = 0; c < 4; c++) { v[c] = src[threadIdx.x + 256 * c]; s += v[c] * v[c]; }
  red[threadIdx.x] = s;
  __syncthreads();
  for (int off = 128; off > 0; off >>= 1) {
    if (threadIdx.x < off) red[threadIdx.x] += red[threadIdx.x + off];
    __syncthreads();
  }
  float inv = 1.0f / fmaxf(sqrtf(red[0]), 1e-12f);
  #pragma unroll
  for (int c = 0; c < 4; c++) dst[threadIdx.x + 256 * c] = f2b(v[c] * inv);
}

// ---------------- skipgram gather from T1 ----------------
__global__ __launch_bounds__(256) void skipgram_gather(const u16* __restrict__ T1,
    const int* __restrict__ pu, const int* __restrict__ pv, const int* __restrict__ nv,
    float* __restrict__ partial) {
  __shared__ float red[256];
  int s = blockIdx.x * 256 + threadIdx.x;
  float loss = 0.f;
  if (s < BATCH) {
    const u16* trow = T1 + (size_t)pu[s] * 2048;
    const int* nvb = nv + (size_t)s * 5;
    float ap = b2f(trow[pv[s]]);
    ap = fminf(fmaxf(ap, -10.f), 10.f); loss = log1pf(expf(-ap));
    #pragma unroll
    for (int k = 0; k < 5; k++) {
      float a = b2f(trow[nvb[k]]);
      a = fminf(fmaxf(a, -10.f), 10.f);
      loss += log1pf(expf(a));
    }
  }
  red[threadIdx.x] = loss;
  __syncthreads();
  for (int off = 128; off > 0; off >>= 1) {
    if (threadIdx.x < off) red[threadIdx.x] += red[threadIdx.x + off];
    __syncthreads();
  }
  if (threadIdx.x == 0) partial[blockIdx.x] = red[0];
}

// ---------------- edge gather from T2 + final loss reduce (block 1563) ----------------
__global__ __launch_bounds__(256) void edge_loss(const float* __restrict__ T2,
    const float* __restrict__ partial,
    const int* __restrict__ ps, const int* __restrict__ pd,
    const int* __restrict__ ns, const int* __restrict__ nd,
    float* __restrict__ out) {
  if (blockIdx.x == 1563) {
    __shared__ float red[256];
    float s = 0.f;
    for (int i = threadIdx.x; i < 391; i += 256) s += partial[i];
    red[threadIdx.x] = s;
    __syncthreads();
    for (int off = 128; off > 0; off >>= 1) {
      if (threadIdx.x < off) red[threadIdx.x] += red[threadIdx.x + off];
      __syncthreads();
    }
    if (threadIdx.x == 0) out[0] = red[0] / (float)BATCH;
    return;
  }
  int e = blockIdx.x * 256 + threadIdx.x;
  if (e >= 2 * EPE) return;
  int src, dst;
  if (e < EPE) { src = ps[e]; dst = pd[e]; }
  else         { src = ns[e - EPE]; dst = nd[e - EPE]; }
  out[1 + e] = T2[(size_t)src * 1024 + dst];
}

// ---------------- launch ----------------
extern "C" void kernel_launch(void* const* d_in, const int* in_sizes, int n_in,
                              void* d_out, int out_size, void* d_ws, size_t ws_size,
                              hipStream_t stream) {
  const float* node_embed    = (const float*)d_in[0];
  const float* context_embed = (const float*)d_in[1];
  const float* adj           = (const float*)d_in[2];
  const float* W1            = (const float*)d_in[3];
  const float* b1            = (const float*)d_in[4];
  const float* W2            = (const float*)d_in[5];
  const float* b2            = (const float*)d_in[6];
  const int* pos_u   = (const int*)d_in[7];
  const int* pos_v   = (const int*)d_in[8];
  const int* neg_v   = (const int*)d_in[9];
  const int* pos_src = (const int*)d_in[10];
  const int* pos_dst = (const int*)d_in[11];
  const int* neg_src = (const int*)d_in[12];
  const int* neg_dst = (const int*)d_in[13];
  float* out = (float*)d_out;

  char* ws = (char*)d_ws;
  u16*   Ap    = (u16*)(ws + OFF_AP);
  u16*   ATp   = (u16*)(ws + OFF_ATP);
  u16*   Sp    = (u16*)(ws + OFF_SP);
  u16*   T1    = (u16*)(ws + OFF_T1);
  float* G     = (float*)(ws + OFF_G);
  float* Gt    = (float*)(ws + OFF_GT);
  u16*   Gns   = (u16*)(ws + OFF_GNS);
  u16*   Gndt  = (u16*)(ws + OFF_GNDT);
  u16*   W1At  = (u16*)(ws + OFF_W1AT);
  u16*   W1Bt  = (u16*)(ws + OFF_W1BT);
  u16*   w2t   = (u16*)(ws + OFF_W2T);
  u16*   hid   = (u16*)(ws + OFF_HID);
  u16*   nep   = (u16*)(ws + OFF_NEP);
  u16*   cep   = (u16*)(ws + OFF_CEP);
  u16*   hsrcp = (u16*)(ws + OFF_HSRC);
  u16*   hdstp = (u16*)(ws + OFF_HDST);
  float* T2    = (float*)(ws + OFF_T2);
  float* degs  = (float*)(ws + OFF_DEGS);
  float* degd  = (float*)(ws + OFF_DEGD);
  float* part  = (float*)(ws + OFF_PART);

  // 1. all packs + degrees
  prep<<<2496, 256, 0, stream>>>(adj, W1, W2, node_embed, context_embed,
                                 Ap, ATp, W1At, W1Bt, w2t, nep, cep, hsrcp, hdstp, degd, degs);

  // 2. T1 = ne @ ce^T (2048x2048, K=128) -> bf16 table
  gemm_bt<0, 2, 2><<<dim3(32, 32), 256, 0, stream>>>(nep, cep, nullptr, nullptr, 128, 128, 128,
      T1, 2048, nullptr, nullptr, nullptr, nullptr, nullptr, nullptr, nullptr, nullptr);

  // 3. skipgram partial sums
  skipgram_gather<<<391, 256, 0, stream>>>(T1, pos_u, pos_v, neg_v, part);

  // 4. S = A A^T (1024^3, exact integers)
  gemm_bt<0, 1, 1><<<dim3(32, 32), 256, 0, stream>>>(Ap, Ap, nullptr, nullptr, 1024, 1024, 1024,
      Sp, 1024, nullptr, nullptr, nullptr, nullptr, nullptr, nullptr, nullptr, nullptr);

  // 5. G = (S @ A) * A / (degs degd^T); writes G and G^T (reuses T1 space)
  gemm_bt<1, 1, 1><<<dim3(32, 32), 256, 0, stream>>>(Sp, ATp, nullptr, nullptr, 1024, 1024, 1024,
      nullptr, 0, G, Ap, degs, degd, nullptr, nullptr, nullptr, Gt);

  // 6. row-norms of G and G^T -> bf16 Gns / Gndt
  normk<<<2048, 256, 0, stream>>>(G, Gt, Gns, Gndt);

  // 7. hid = tanh(gamma_hat @ W1 + b1): z=0 src (Gns @ W1Bt^T), z=1 dst (Gndt @ W1At^T)
  gemm_bt<2, 1, 1><<<dim3(32, 8, 2), 256, 0, stream>>>(Gns, W1Bt, Gndt, W1At, 1024, 1024, 1024,
      hid, 0, nullptr, nullptr, nullptr, nullptr, b1, nullptr, nullptr, nullptr);

  // 8. h[:,128:] = hid @ W2 + b2 -> bf16 into hsrcp/hdstp cols 128..255
  gemm_bt<3, 1, 1><<<dim3(64, 4), 256, 0, stream>>>(hid, w2t, nullptr, nullptr, 256, 256, 256,
      nullptr, 0, nullptr, nullptr, nullptr, nullptr, b2, hsrcp, hdstp, nullptr);

  // 9. T2 = h_src @ h_dst^T (1024x1024, K=256) -> f32 table
  gemm_bt<4, 1, 1><<<dim3(32, 32), 256, 0, stream>>>(hsrcp, hdstp, nullptr, nullptr, 256, 256, 256,
      nullptr, 1024, T2, nullptr, nullptr, nullptr, nullptr, nullptr, nullptr, nullptr);

  // 10. edge gathers + final loss reduce
  edge_loss<<<1564, 256, 0, stream>>>(T2, part, pos_src, pos_dst, neg_src, neg_dst, out);
}

// Round 5
// 111.332 us; speedup vs baseline: 3.4137x; 1.0209x over previous
//
#include <hip/hip_runtime.h>
#include <hip/hip_bf16.h>

typedef __attribute__((ext_vector_type(8))) short bf16x8;
typedef __attribute__((ext_vector_type(4))) float f32x4;
typedef unsigned short u16;

#define BATCH 100000
#define EPE 200000

// ---- workspace layout (bytes), peak ~27.3 MB ----
#define OFF_AP    ((size_t)0)          // u16 [1024*1024]
#define OFF_ATP   ((size_t)2097152)    // u16 [1024*1024]
#define OFF_SP    ((size_t)4194304)    // u16 [1024*1024]
#define OFF_T1    ((size_t)6291456)    // u16 [2048*2048] (dead after skipgram_gather)
#define OFF_G     ((size_t)6291456)    // f32 [1024*1024] (reuses T1 space)
#define OFF_GT    ((size_t)10485760)   // f32 [1024*1024]
#define OFF_GNS   ((size_t)14680064)   // u16 [1024*1024]
#define OFF_GNDT  ((size_t)16777216)   // u16 [1024*1024]
#define OFF_W1AT  ((size_t)18874368)   // u16 [256*1024]
#define OFF_W1BT  ((size_t)19398656)   // u16 [256*1024]
#define OFF_W2T   ((size_t)19922944)   // u16 [128*256]
#define OFF_HID   ((size_t)19988480)   // u16 [2048*256]
#define OFF_NEP   ((size_t)21037056)   // u16 [2048*128]
#define OFF_CEP   ((size_t)21561344)   // u16 [2048*128]
#define OFF_HSRC  ((size_t)22085632)   // u16 [1024*256]
#define OFF_HDST  ((size_t)22609920)   // u16 [1024*256]
#define OFF_T2    ((size_t)23134208)   // f32 [1024*1024]
#define OFF_DEGS  ((size_t)27328512)   // f32 [1024]
#define OFF_DEGD  ((size_t)27332608)   // f32 [1024]
#define OFF_PART  ((size_t)27336704)   // f32 [391]

__device__ __forceinline__ u16 f2b(float f) {
  union { float f; unsigned u; } v; v.f = f;
  unsigned r = v.u + 0x7fffu + ((v.u >> 16) & 1u);
  return (u16)(r >> 16);
}
__device__ __forceinline__ float b2f(u16 h) {
  union { unsigned u; float f; } v; v.u = ((unsigned)h) << 16;
  return v.f;
}

#define AS1C(p) ((const __attribute__((address_space(1))) void*)(p))
#define AS3(p)  ((__attribute__((address_space(3))) void*)(p))

// ---------------- fused prep: all packs + degrees, fully coalesced ----------------
// blocks: [0,256)    adj tile pack+transpose (64x64 LDS tiles)
//         [256,384)  W1 transpose via LDS tiles (half, jt, ht)
//         [384,392)  W2 transpose via LDS tiles
//         [392,1416) ne/ce/h-halves elementwise pack
//         [1416,1448) degd colsums; [1448,1480) degs rowsums
__global__ __launch_bounds__(256) void prep(const float* __restrict__ adj,
    const float* __restrict__ W1, const float* __restrict__ W2,
    const float* __restrict__ ne, const float* __restrict__ ce,
    u16* __restrict__ Ap, u16* __restrict__ ATp,
    u16* __restrict__ W1At, u16* __restrict__ W1Bt, u16* __restrict__ w2t,
    u16* __restrict__ nep, u16* __restrict__ cep,
    u16* __restrict__ hsrcp, u16* __restrict__ hdstp,
    float* __restrict__ degd, float* __restrict__ degs) {
  __shared__ float tile[64][65];
  __shared__ float redf[256];
  int b = blockIdx.x;
  int t = threadIdx.x;
  int tx = t & 63, ty = t >> 6;
  if (b < 256) {
    int tr = b >> 4, tc = b & 15;
    #pragma unroll
    for (int p = 0; p < 16; p++) {
      int r = p * 4 + ty;
      int gr = tr * 64 + r, gc = tc * 64 + tx;
      float v = (gr < 1000 && gc < 1000) ? adj[(size_t)gr * 2000 + 1000 + gc] : 0.f;
      Ap[(size_t)gr * 1024 + gc] = f2b(v);
      tile[r][tx] = v;
    }
    __syncthreads();
    #pragma unroll
    for (int p = 0; p < 16; p++) {
      int r = p * 4 + ty;
      ATp[(size_t)(tc * 64 + r) * 1024 + tr * 64 + tx] = f2b(tile[tx][r]);
    }
  } else if (b < 384) {
    // W1 transpose: out[h][j] = W1[half*1000 + j][h]
    int b2 = b - 256;
    int half = b2 >> 6, rem = b2 & 63;
    int jt = rem >> 2, ht = rem & 3;
    #pragma unroll
    for (int p = 0; p < 16; p++) {
      int r = p * 4 + ty;                       // j-local
      int j = jt * 64 + r;
      tile[r][tx] = (j < 1000) ? W1[(size_t)(half * 1000 + j) * 256 + ht * 64 + tx] : 0.f;
    }
    __syncthreads();
    u16* outp = half ? W1Bt : W1At;
    #pragma unroll
    for (int p = 0; p < 16; p++) {
      int r = p * 4 + ty;                       // h-local
      outp[(size_t)(ht * 64 + r) * 1024 + jt * 64 + tx] = f2b(tile[tx][r]);
    }
  } else if (b < 392) {
    // W2 transpose: w2t[d][k] = W2[k][d]
    int b3 = b - 384;
    int dt = b3 >> 2, kt = b3 & 3;
    #pragma unroll
    for (int p = 0; p < 16; p++) {
      int r = p * 4 + ty;                       // k-local
      tile[r][tx] = W2[(size_t)(kt * 64 + r) * 128 + dt * 64 + tx];
    }
    __syncthreads();
    #pragma unroll
    for (int p = 0; p < 16; p++) {
      int r = p * 4 + ty;                       // d-local
      w2t[(size_t)(dt * 64 + r) * 256 + kt * 64 + tx] = f2b(tile[tx][r]);
    }
  } else if (b < 1416) {
    int idx = (b - 392) * 256 + t;              // 2048*128
    int i = idx >> 7, d = idx & 127;
    float nv = (i < 2000) ? ne[(size_t)i * 128 + d] : 0.f;
    float cv = (i < 2000) ? ce[(size_t)i * 128 + d] : 0.f;
    u16 nb = f2b(nv);
    nep[idx] = nb;
    cep[idx] = f2b(cv);
    if (i < 1000)                   hsrcp[(size_t)i * 256 + d] = nb;
    else if (i < 1024)              hsrcp[(size_t)i * 256 + d] = 0;
    if (i >= 1000 && i < 2000)      hdstp[(size_t)(i - 1000) * 256 + d] = nb;
    else if (i >= 2000 && i < 2024) hdstp[(size_t)(i - 1000) * 256 + d] = 0;
  } else if (b < 1448) {
    // degd[j] = colsum of A
    int jb = b - 1416;
    int cx = t & 31, ry = t >> 5;
    int j = jb * 32 + cx;
    float s = 0.f;
    if (j < 1000)
      for (int i = ry; i < 1000; i += 8) s += adj[(size_t)i * 2000 + 1000 + j];
    redf[t] = s;
    __syncthreads();
    if (ry == 0) {
      float tot = 0.f;
      #pragma unroll
      for (int k = 0; k < 8; k++) tot += redf[k * 32 + cx];
      degd[j] = (j < 1000) ? tot : 0.f;
    }
  } else {
    // degs[i] = rowsum of A
    int ib = b - 1448;
    int r = t >> 3, c8 = t & 7;
    int i = ib * 32 + r;
    float s = 0.f;
    if (i < 1000)
      for (int k = c8; k < 1000; k += 8) s += adj[(size_t)i * 2000 + 1000 + k];
    redf[t] = s;
    __syncthreads();
    if (c8 == 0) {
      float tot = 0.f;
      #pragma unroll
      for (int k = 0; k < 8; k++) tot += redf[r * 8 + k];
      degs[i] = (i < 1000) ? tot : 0.f;
    }
  }
}

// ---------------- generalized bf16 MFMA GEMM, 2-phase double-buffered ----------------
// C = A * BT^T. BM=32*MR, BN=32*NR, BK=64, 4 waves (2x2).
// EPI 0: outb bf16 (ldo)
// EPI 1: g = C*apack/(degs[r]*degd[c]); G coalesced; Gt via in-block LDS transpose
// EPI 2: hid: bf16(tanh(C + bias[col])) at [(z*1024+row)*256+col]
// EPI 3: bf16(C + bias[col]) -> hsrcp/hdstp cols 128..255 (rows 0..1023 src, 1024.. dst)
// EPI 4: outf f32 (ldo)
template <int EPI, int MR, int NR>
__global__ __launch_bounds__(256) void gemm_bt(
    const u16* __restrict__ A, const u16* __restrict__ BT,
    const u16* __restrict__ A2, const u16* __restrict__ BT2,
    int K, int lda, int ldbt,
    u16* __restrict__ outb, int ldo,
    float* __restrict__ outf,
    const u16* __restrict__ apack,
    const float* __restrict__ degs, const float* __restrict__ degd,
    const float* __restrict__ bias,
    u16* __restrict__ hsrcp, u16* __restrict__ hdstp,
    float* __restrict__ outf2)
{
  constexpr int BMt = 32 * MR, BNt = 32 * NR;
  __shared__ u16 As[2][BMt * 64];
  __shared__ u16 Bs[2][BNt * 64];
  const int t = threadIdx.x;
  const int w = t >> 6, lane = t & 63;
  const int brow = blockIdx.x * BMt, bcol = blockIdx.y * BNt;
  const int wr = w >> 1, wc = w & 1;
  const int r16 = lane & 15, kg = lane >> 4;
  const u16* Au = (blockIdx.z == 0) ? A : A2;
  const u16* Bu = (blockIdx.z == 0) ? BT : BT2;

  f32x4 acc[MR][NR];
  #pragma unroll
  for (int m = 0; m < MR; m++)
    #pragma unroll
    for (int n = 0; n < NR; n++) {
      f32x4 z = {0.f, 0.f, 0.f, 0.f};
      acc[m][n] = z;
    }

  auto stage = [&](int buf, int k0) {
    #pragma unroll
    for (int it = 0; it < MR; ++it) {
      int chunk = it * 256 + t;
      const u16* ga = Au + (size_t)(brow + (chunk >> 3)) * lda + k0 + (chunk & 7) * 8;
      __builtin_amdgcn_global_load_lds(AS1C(ga), AS3(As[buf] + (size_t)chunk * 8), 16, 0, 0);
    }
    #pragma unroll
    for (int it = 0; it < NR; ++it) {
      int chunk = it * 256 + t;
      const u16* gb = Bu + (size_t)(bcol + (chunk >> 3)) * ldbt + k0 + (chunk & 7) * 8;
      __builtin_amdgcn_global_load_lds(AS1C(gb), AS3(Bs[buf] + (size_t)chunk * 8), 16, 0, 0);
    }
  };

  const int nst = K >> 6;
  stage(0, 0);
  int cur = 0;
  for (int s = 0; s < nst; ++s) {
    __syncthreads();                       // drains vmcnt+lgkm: buf[cur] ready, prev reads done
    if (s + 1 < nst) stage(cur ^ 1, (s + 1) << 6);
    const u16* Asc = As[cur];
    const u16* Bsc = Bs[cur];
    #pragma unroll
    for (int kk = 0; kk < 2; ++kk) {
      bf16x8 af[MR], bfr[NR];
      #pragma unroll
      for (int m = 0; m < MR; m++)
        af[m] = *(const bf16x8*)&Asc[(wr * (MR * 16) + m * 16 + r16) * 64 + kk * 32 + kg * 8];
      #pragma unroll
      for (int n = 0; n < NR; n++)
        bfr[n] = *(const bf16x8*)&Bsc[(wc * (NR * 16) + n * 16 + r16) * 64 + kk * 32 + kg * 8];
      #pragma unroll
      for (int m = 0; m < MR; m++)
        #pragma unroll
        for (int n = 0; n < NR; n++)
          acc[m][n] = __builtin_amdgcn_mfma_f32_16x16x32_bf16(af[m], bfr[n], acc[m][n], 0, 0, 0);
    }
    cur ^= 1;
  }

  if constexpr (EPI == 1) {
    // 32x32 tile (MR=NR=1): write G coalesced, stash in LDS, write Gt coalesced
    __shared__ float gtile[32][33];
    #pragma unroll
    for (int j = 0; j < 4; j++) {
      int lr = wr * 16 + kg * 4 + j;
      int lc = wc * 16 + r16;
      int row = brow + lr, col = bcol + lc;
      float val = acc[0][0][j];
      float a = b2f(apack[(size_t)row * 1024 + col]);
      float p2 = degs[row] * degd[col];
      float g = (p2 > 0.f) ? (val * a) / p2 : 0.f;
      outf[(size_t)row * 1024 + col] = g;
      gtile[lr][lc] = g;
    }
    __syncthreads();
    #pragma unroll
    for (int p = 0; p < 4; p++) {
      int idx = p * 256 + t;
      int rr = idx >> 5, cc = idx & 31;
      outf2[(size_t)(bcol + rr) * 1024 + brow + cc] = gtile[cc][rr];
    }
    return;
  }

  #pragma unroll
  for (int m = 0; m < MR; m++) {
    #pragma unroll
    for (int n = 0; n < NR; n++) {
      #pragma unroll
      for (int j = 0; j < 4; j++) {
        int row = brow + wr * (MR * 16) + m * 16 + kg * 4 + j;
        int col = bcol + wc * (NR * 16) + n * 16 + r16;
        float val = acc[m][n][j];
        if constexpr (EPI == 0) {
          outb[(size_t)row * ldo + col] = f2b(val);
        } else if constexpr (EPI == 2) {
          outb[(size_t)(blockIdx.z * 1024 + row) * 256 + col] = f2b(tanhf(val + bias[col]));
        } else if constexpr (EPI == 3) {
          u16 hv = f2b(val + bias[col]);
          if (row < 1024) hsrcp[(size_t)row * 256 + 128 + col] = hv;
          else            hdstp[(size_t)(row - 1024) * 256 + 128 + col] = hv;
        } else if constexpr (EPI == 4) {
          outf[(size_t)row * ldo + col] = val;
        }
      }
    }
  }
}

// ---------------- fused norms: blocks [0,1024) rows of G -> Gns; [1024,2048) rows of Gt -> Gndt
__global__ __launch_bounds__(256) void normk(const float* __restrict__ G, const float* __restrict__ Gt,
                                             u16* __restrict__ Gns, u16* __restrict__ Gndt) {
  __shared__ float red[256];
  int b = blockIdx.x;
  const float* src = (b < 1024) ? (G + (size_t)b * 1024) : (Gt + (size_t)(b - 1024) * 1024);
  u16* dst = (b < 1024) ? (Gns + (size_t)b * 1024) : (Gndt + (size_t)(b - 1024) * 1024);
  float v[4];
  float s = 0.f;
  #pragma unroll
  for (int c = 0; c < 4; c++) { v[c] = src[threadIdx.x + 256 * c]; s += v[c] * v[c]; }
  red[threadIdx.x] = s;
  __syncthreads();
  for (int off = 128; off > 0; off >>= 1) {
    if (threadIdx.x < off) red[threadIdx.x] += red[threadIdx.x + off];
    __syncthreads();
  }
  float inv = 1.0f / fmaxf(sqrtf(red[0]), 1e-12f);
  #pragma unroll
  for (int c = 0; c < 4; c++) dst[threadIdx.x + 256 * c] = f2b(v[c] * inv);
}

// ---------------- skipgram gather from T1 ----------------
__global__ __launch_bounds__(256) void skipgram_gather(const u16* __restrict__ T1,
    const int* __restrict__ pu, const int* __restrict__ pv, const int* __restrict__ nv,
    float* __restrict__ partial) {
  __shared__ float red[256];
  int s = blockIdx.x * 256 + threadIdx.x;
  float loss = 0.f;
  if (s < BATCH) {
    const u16* trow = T1 + (size_t)pu[s] * 2048;
    const int* nvb = nv + (size_t)s * 5;
    float ap = b2f(trow[pv[s]]);
    ap = fminf(fmaxf(ap, -10.f), 10.f); loss = log1pf(expf(-ap));
    #pragma unroll
    for (int k = 0; k < 5; k++) {
      float a = b2f(trow[nvb[k]]);
      a = fminf(fmaxf(a, -10.f), 10.f);
      loss += log1pf(expf(a));
    }
  }
  red[threadIdx.x] = loss;
  __syncthreads();
  for (int off = 128; off > 0; off >>= 1) {
    if (threadIdx.x < off) red[threadIdx.x] += red[threadIdx.x + off];
    __syncthreads();
  }
  if (threadIdx.x == 0) partial[blockIdx.x] = red[0];
}

// ---------------- edge gather from T2 + final loss reduce (block 1563) ----------------
__global__ __launch_bounds__(256) void edge_loss(const float* __restrict__ T2,
    const float* __restrict__ partial,
    const int* __restrict__ ps, const int* __restrict__ pd,
    const int* __restrict__ ns, const int* __restrict__ nd,
    float* __restrict__ out) {
  if (blockIdx.x == 1563) {
    __shared__ float red[256];
    float s = 0.f;
    for (int i = threadIdx.x; i < 391; i += 256) s += partial[i];
    red[threadIdx.x] = s;
    __syncthreads();
    for (int off = 128; off > 0; off >>= 1) {
      if (threadIdx.x < off) red[threadIdx.x] += red[threadIdx.x + off];
      __syncthreads();
    }
    if (threadIdx.x == 0) out[0] = red[0] / (float)BATCH;
    return;
  }
  int e = blockIdx.x * 256 + threadIdx.x;
  if (e >= 2 * EPE) return;
  int src, dst;
  if (e < EPE) { src = ps[e]; dst = pd[e]; }
  else         { src = ns[e - EPE]; dst = nd[e - EPE]; }
  out[1 + e] = T2[(size_t)src * 1024 + dst];
}

// ---------------- launch ----------------
extern "C" void kernel_launch(void* const* d_in, const int* in_sizes, int n_in,
                              void* d_out, int out_size, void* d_ws, size_t ws_size,
                              hipStream_t stream) {
  const float* node_embed    = (const float*)d_in[0];
  const float* context_embed = (const float*)d_in[1];
  const float* adj           = (const float*)d_in[2];
  const float* W1            = (const float*)d_in[3];
  const float* b1            = (const float*)d_in[4];
  const float* W2            = (const float*)d_in[5];
  const float* b2            = (const float*)d_in[6];
  const int* pos_u   = (const int*)d_in[7];
  const int* pos_v   = (const int*)d_in[8];
  const int* neg_v   = (const int*)d_in[9];
  const int* pos_src = (const int*)d_in[10];
  const int* pos_dst = (const int*)d_in[11];
  const int* neg_src = (const int*)d_in[12];
  const int* neg_dst = (const int*)d_in[13];
  float* out = (float*)d_out;

  char* ws = (char*)d_ws;
  u16*   Ap    = (u16*)(ws + OFF_AP);
  u16*   ATp   = (u16*)(ws + OFF_ATP);
  u16*   Sp    = (u16*)(ws + OFF_SP);
  u16*   T1    = (u16*)(ws + OFF_T1);
  float* G     = (float*)(ws + OFF_G);
  float* Gt    = (float*)(ws + OFF_GT);
  u16*   Gns   = (u16*)(ws + OFF_GNS);
  u16*   Gndt  = (u16*)(ws + OFF_GNDT);
  u16*   W1At  = (u16*)(ws + OFF_W1AT);
  u16*   W1Bt  = (u16*)(ws + OFF_W1BT);
  u16*   w2t   = (u16*)(ws + OFF_W2T);
  u16*   hid   = (u16*)(ws + OFF_HID);
  u16*   nep   = (u16*)(ws + OFF_NEP);
  u16*   cep   = (u16*)(ws + OFF_CEP);
  u16*   hsrcp = (u16*)(ws + OFF_HSRC);
  u16*   hdstp = (u16*)(ws + OFF_HDST);
  float* T2    = (float*)(ws + OFF_T2);
  float* degs  = (float*)(ws + OFF_DEGS);
  float* degd  = (float*)(ws + OFF_DEGD);
  float* part  = (float*)(ws + OFF_PART);

  // 1. all packs + degrees (coalesced LDS-tile transposes)
  prep<<<1480, 256, 0, stream>>>(adj, W1, W2, node_embed, context_embed,
                                 Ap, ATp, W1At, W1Bt, w2t, nep, cep, hsrcp, hdstp, degd, degs);

  // 2. T1 = ne @ ce^T (2048x2048, K=128) -> bf16 table
  gemm_bt<0, 2, 2><<<dim3(32, 32), 256, 0, stream>>>(nep, cep, nullptr, nullptr, 128, 128, 128,
      T1, 2048, nullptr, nullptr, nullptr, nullptr, nullptr, nullptr, nullptr, nullptr);

  // 3. skipgram partial sums
  skipgram_gather<<<391, 256, 0, stream>>>(T1, pos_u, pos_v, neg_v, part);

  // 4. S = A A^T (1024^3, exact integers)
  gemm_bt<0, 1, 1><<<dim3(32, 32), 256, 0, stream>>>(Ap, Ap, nullptr, nullptr, 1024, 1024, 1024,
      Sp, 1024, nullptr, nullptr, nullptr, nullptr, nullptr, nullptr, nullptr, nullptr);

  // 5. G = (S @ A) * A / (degs degd^T); writes G and G^T (coalesced via LDS transpose)
  gemm_bt<1, 1, 1><<<dim3(32, 32), 256, 0, stream>>>(Sp, ATp, nullptr, nullptr, 1024, 1024, 1024,
      nullptr, 0, G, Ap, degs, degd, nullptr, nullptr, nullptr, Gt);

  // 6. row-norms of G and G^T -> bf16 Gns / Gndt
  normk<<<2048, 256, 0, stream>>>(G, Gt, Gns, Gndt);

  // 7. hid = tanh(gamma_hat @ W1 + b1): z=0 src (Gns @ W1Bt^T), z=1 dst (Gndt @ W1At^T)
  gemm_bt<2, 1, 1><<<dim3(32, 8, 2), 256, 0, stream>>>(Gns, W1Bt, Gndt, W1At, 1024, 1024, 1024,
      hid, 0, nullptr, nullptr, nullptr, nullptr, b1, nullptr, nullptr, nullptr);

  // 8. h[:,128:] = hid @ W2 + b2 -> bf16 into hsrcp/hdstp cols 128..255
  gemm_bt<3, 1, 1><<<dim3(64, 4), 256, 0, stream>>>(hid, w2t, nullptr, nullptr, 256, 256, 256,
      nullptr, 0, nullptr, nullptr, nullptr, nullptr, b2, hsrcp, hdstp, nullptr);

  // 9. T2 = h_src @ h_dst^T (1024x1024, K=256) -> f32 table
  gemm_bt<4, 1, 1><<<dim3(32, 32), 256, 0, stream>>>(hsrcp, hdstp, nullptr, nullptr, 256, 256, 256,
      nullptr, 1024, T2, nullptr, nullptr, nullptr, nullptr, nullptr, nullptr, nullptr);

  // 10. edge gathers + final loss reduce
  edge_loss<<<1564, 256, 0, stream>>>(T2, part, pos_src, pos_dst, neg_src, neg_dst, out);
}